// Round 7
// baseline (34.209 us; speedup 1.0000x reference)
//
#include <hip/hip_runtime.h>
#include <math.h>

// out[c*65536 + pix] = in[(rho(pix)*256 + th(pix))*512 + c] * WSUM
// in : (1,256,256,512) f32 NHWC-flat ; out: warped-(C,H,W) flat f32.
// v7: CHANNEL-partitioned XCD swizzle. XCD k (= b%8) owns channel slice
// [64k,64k+64) for ALL rows -> disjoint input byte-ranges per XCD, zero
// cross-L2 duplicate fetch (v6's row-band split re-fetched shared cells
// once per XCD). Rows advance sequentially per XCD so +-3-row cell reuse
// stays L2-resident. LDS XOR-swizzle transpose + nt coalesced stores kept.

typedef float v4f __attribute__((ext_vector_type(4)));

__global__ __launch_bounds__(256) void InverseLogPolar_kernel(
        const float* __restrict__ in, float* __restrict__ out) {
    __shared__ int   sBase[256];
    __shared__ float tile[64 * 256];   // [ch_row r][px p], addr = r*256 + (p ^ (((r>>2)&7)<<2))

    const int b    = blockIdx.x;
    const int ct   = b & 7;            // XCD k owns channel tile k
    const int row  = b >> 3;           // rows sweep 0..255 within each XCD
    const int t    = threadIdx.x;
    const int pix0 = row << 8;
    const int c0   = ct << 6;          // 64 channels per block

    // ---- inverse log-polar index, float64, mirrors numpy op-for-op ----
    {
        const double dy = (double)row - 127.5;
        const double dx = (double)t   - 127.5;
        const double r  = sqrt(dx * dx + dy * dy);
        const double rmax  = sqrt(127.5 * 127.5 + 127.5 * 127.5);
        const double lrmax = log(rmax);
        double rho   = (r > 0.5) ? (log(fmax(r, 1e-6)) / lrmax) * 255.0 : 0.0;
        double theta = ((atan2(dy, dx) + M_PI) / (2.0 * M_PI)) * 255.0;
        double rr = fmin(fmax(rint(rho),   0.0), 255.0);
        double tt = fmin(fmax(rint(theta), 0.0), 255.0);
        sBase[t] = ((int)rr << 17) | ((int)tt << 9);   // (rho*256 + th) * 512
    }
    __syncthreads();

    const float WSUM = (float)(0.2989 + 0.587 + 0.114);

    // ---- phase 1: gather global -> registers ----
    // chunk k: pixel p = k>>4, channel offset cj = (k&15)*4.
    // 16 lanes per pixel => 256B contiguous run per gathered cell slice.
    float4 v[16];
    #pragma unroll
    for (int it = 0; it < 16; ++it) {
        const int k = (it << 8) + t;
        const int p = k >> 4;
        const int cj = (k & 15) << 2;
        v[it] = *reinterpret_cast<const float4*>(in + sBase[p] + c0 + cj);
    }
    // ---- registers -> LDS transpose (swizzled; 2-way bank = free) ----
    #pragma unroll
    for (int it = 0; it < 16; ++it) {
        const int k = (it << 8) + t;
        const int p = k >> 4;
        const int cj = (k & 15) << 2;
        const int pp = p ^ ((k & 7) << 2);   // ((r>>2)&7)<<2 with r=cj+d, d<4
        float* r0 = &tile[cj * 256 + pp];
        r0[0]       = v[it].x * WSUM;
        r0[256]     = v[it].y * WSUM;
        r0[512]     = v[it].z * WSUM;
        r0[768]     = v[it].w * WSUM;
    }
    __syncthreads();

    // ---- phase 2: LDS -> global, conflict-free b128, 1KB coalesced nt stores ----
    const int l = t & 63;
    const int w = t >> 6;
    #pragma unroll
    for (int it2 = 0; it2 < 16; ++it2) {
        const int c = (w << 4) + it2;                       // wave-uniform channel row
        const int pl = (l ^ ((c >> 2) & 7)) << 2;           // swizzled physical pixel group
        const v4f o = *reinterpret_cast<const v4f*>(&tile[c * 256 + pl]);
        __builtin_nontemporal_store(
            o, reinterpret_cast<v4f*>(out + ((size_t)(c0 + c) << 16) + pix0 + (pl ^ ((((c >> 2) & 7) << 2)))));
    }
}

extern "C" void kernel_launch(void* const* d_in, const int* in_sizes, int n_in,
                              void* d_out, int out_size, void* d_ws, size_t ws_size,
                              hipStream_t stream) {
    const float* in = (const float*)d_in[0];
    float* out = (float*)d_out;
    dim3 grid(2048);    // b = row*8 + ct ; ct = b&7 -> XCD-by-channel partition
    dim3 block(256);
    hipLaunchKernelGGL(InverseLogPolar_kernel, grid, block, 0, stream, in, out);
}

// Round 8
// 32.878 us; speedup vs baseline: 1.0405x; 1.0405x over previous
//
#include <hip/hip_runtime.h>
#include <math.h>

// out[c*65536 + pix] = in[(rho(pix)*256 + th(pix))*512 + c] * WSUM
// in : (1,256,256,512) f32 NHWC-flat ; out: warped-(C,H,W) flat f32.
// v8: v6 structure (row-band XCD swizzle + XOR-swizzled LDS transpose + nt
// coalesced stores) but 32-ch x 256-px tile: 33KB LDS -> 4 blocks/CU
// (16 waves/CU, 2x v6's TLP) so gather latency of one block hides behind
// transpose/store phases of the others. Bank behavior identical to v6:
// phase-1 scalar writes 2-way (free), phase-2 b128 reads conflict-free.

typedef float v4f __attribute__((ext_vector_type(4)));

__global__ __launch_bounds__(256) void InverseLogPolar_kernel(
        const float* __restrict__ in, float* __restrict__ out) {
    __shared__ int   sBase[256];
    __shared__ float tile[32 * 256];   // [ch_row r][px p], addr = r*256 + (p ^ (((r>>2)&7)<<2))

    const int b    = blockIdx.x;
    const int row  = ((b & 7) << 5) | ((b >> 3) & 31);  // XCD k owns rows [32k, 32k+32)
    const int ct   = b >> 8;                            // channel tile 0..15
    const int t    = threadIdx.x;
    const int pix0 = row << 8;
    const int c0   = ct << 5;                           // 32 channels per block

    // ---- inverse log-polar index, float64, mirrors numpy op-for-op ----
    {
        const double dy = (double)row - 127.5;
        const double dx = (double)t   - 127.5;
        const double r  = sqrt(dx * dx + dy * dy);
        const double rmax  = sqrt(127.5 * 127.5 + 127.5 * 127.5);
        const double lrmax = log(rmax);
        double rho   = (r > 0.5) ? (log(fmax(r, 1e-6)) / lrmax) * 255.0 : 0.0;
        double theta = ((atan2(dy, dx) + M_PI) / (2.0 * M_PI)) * 255.0;
        double rr = fmin(fmax(rint(rho),   0.0), 255.0);
        double tt = fmin(fmax(rint(theta), 0.0), 255.0);
        sBase[t] = ((int)rr << 17) | ((int)tt << 9);   // (rho*256 + th) * 512
    }
    __syncthreads();

    const float WSUM = (float)(0.2989 + 0.587 + 0.114);

    // ---- phase 1: gather global -> registers ----
    // chunk k (0..2047): pixel p = k>>3, channel float4 cj = (k&7)*4.
    // 8 lanes per pixel => 128B contiguous run per gathered cell slice.
    float4 v[8];
    #pragma unroll
    for (int it = 0; it < 8; ++it) {
        const int k = (it << 8) + t;
        const int p = k >> 3;
        const int cj = (k & 7) << 2;
        v[it] = *reinterpret_cast<const float4*>(in + sBase[p] + c0 + cj);
    }
    // ---- registers -> LDS transpose (swizzled; 2-way bank = free) ----
    #pragma unroll
    for (int it = 0; it < 8; ++it) {
        const int k = (it << 8) + t;
        const int p = k >> 3;
        const int cj = (k & 7) << 2;
        const int pp = p ^ ((k & 7) << 2);   // s(r) = ((r>>2)&7)<<2, r = cj+d
        float* r0 = &tile[cj * 256 + pp];
        r0[0]   = v[it].x * WSUM;
        r0[256] = v[it].y * WSUM;
        r0[512] = v[it].z * WSUM;
        r0[768] = v[it].w * WSUM;
    }
    __syncthreads();

    // ---- phase 2: LDS -> global, conflict-free b128, 1KB coalesced nt stores ----
    const int l = t & 63;
    const int w = t >> 6;
    #pragma unroll
    for (int it2 = 0; it2 < 8; ++it2) {
        const int c = (w << 3) + it2;                       // wave-uniform channel row
        const int s = ((c >> 2) & 7) << 2;
        const int pl = (l << 2) ^ s;                        // physical pixel group
        const v4f o = *reinterpret_cast<const v4f*>(&tile[c * 256 + pl]);
        __builtin_nontemporal_store(
            o, reinterpret_cast<v4f*>(out + ((size_t)(c0 + c) << 16) + pix0 + (pl ^ s)));
    }
}

extern "C" void kernel_launch(void* const* d_in, const int* in_sizes, int n_in,
                              void* d_out, int out_size, void* d_ws, size_t ws_size,
                              hipStream_t stream) {
    const float* in = (const float*)d_in[0];
    float* out = (float*)d_out;
    dim3 grid(4096);    // 256 rows x 16 channel tiles, XCD row-band swizzled
    dim3 block(256);
    hipLaunchKernelGGL(InverseLogPolar_kernel, grid, block, 0, stream, in, out);
}